// Round 4
// baseline (109.456 us; speedup 1.0000x reference)
//
#include <hip/hip_runtime.h>
#include <stdint.h>

// CRF forward loss, chunked parallel scan in linear space.
// K2: one wave per 16-step chunk (2048 waves). M <- E_t * M, t descending.
//     A = E_t (row-major LDS), B = M via transposed LDS image TM (all b128),
//     D writes vectorized into TM. Global tile register-prefetched.
//     Gold gathered from the in-register tile (exact f32). len from mask inline.
// K3: per-batch serial alpha matvec over <=32 transposed chunk matrices
//     (lane j reads its contiguous 96B row), register-prefetched.

#define T_LEN 512
#define KK 48
#define NSTART 46
#define NEND 47
#define PITCH 144    // LDS row pitch bytes: 64 bf16 (48 real + 16 zero-pad K) + 16B bank-stagger
#define REGION 6912  // 48 * PITCH
#define WAVE_LDS (2 * REGION)
#define CHB 4608     // 48*48 bf16 chunk matrix (transposed, dense pitch 96) in ws

typedef __attribute__((ext_vector_type(8))) short short8;
typedef __attribute__((ext_vector_type(4))) float f32x4;

__device__ __forceinline__ ushort f2bf(float x) {
  uint32_t u = __float_as_uint(x);
  return (ushort)((u + 0x7FFFu + ((u >> 16) & 1u)) >> 16);
}
__device__ __forceinline__ float bf2f(uint32_t h) { return __uint_as_float(h << 16); }

// per-wave: decode mask encoding (u8 bool / f32 / i32 / i64) and popcount row b.
__device__ __forceinline__ int mask_len(const void* mask, int b, int lane) {
  const uint32_t w0 = ((const uint32_t*)mask)[0];
  const uint32_t w1 = ((const uint32_t*)mask)[1];
  int c = 0;
  if (w0 == 0x01010101u) {
    const unsigned long long* m8 =
        (const unsigned long long*)((const unsigned char*)mask + (size_t)b * T_LEN);
    c = (int)__popcll(m8[lane]);
  } else if (w0 == 0x3F800000u) {
    const float* mf = (const float*)mask + (size_t)b * T_LEN;
#pragma unroll
    for (int j = 0; j < 8; ++j) c += (mf[lane + 64 * j] != 0.0f);
  } else if (w1 == 1u) {
    const uint32_t* mi = (const uint32_t*)mask + (size_t)b * T_LEN;
#pragma unroll
    for (int j = 0; j < 8; ++j) c += (mi[lane + 64 * j] != 0u);
  } else {
    const unsigned long long* ml =
        (const unsigned long long*)mask + (size_t)b * T_LEN;
#pragma unroll
    for (int j = 0; j < 8; ++j) c += (ml[lane + 64 * j] != 0ull);
  }
#pragma unroll
  for (int d = 1; d < 64; d <<= 1) c += __shfl_xor(c, d);
  return c > T_LEN ? T_LEN : (c < 0 ? 0 : c);
}

// ---------------- K2: chunk products ----------------
__global__ __launch_bounds__(256, 2) void k2_chunks(
    const float* __restrict__ scores, const int* __restrict__ targets,
    const void* __restrict__ mask, unsigned char* __restrict__ wsT,
    int* __restrict__ wsExpo, float* __restrict__ wsGold, int nch) {
  __shared__ __align__(16) unsigned char smem[4][WAVE_LDS];
  const int wid = threadIdx.x >> 6, lane = threadIdx.x & 63;
  const int g = blockIdx.x * 4 + wid;
  if (g >= nch) return;
  const int b = g >> 5, cix = g & 31;
  const int len = mask_len(mask, b, lane);
  int steps = len - (cix << 4);
  if (steps <= 0) return;  // never consumed by K3
  if (steps > 16) steps = 16;

  unsigned char* E = smem[wid];        // E_t, row-major, 48 rows x PITCH (K-pad cols 48..63 = 0)
  unsigned char* TM = E + REGION;      // M transposed: TM[c][r], K-pad rows 48..63 = 0

  {  // zero both regions (864 x 16B)
    int4* z = (int4*)E;
#pragma unroll
    for (int q = 0; q < 14; ++q) {
      int idx = q * 64 + lane;
      if (idx < WAVE_LDS / 16) z[idx] = make_int4(0, 0, 0, 0);
    }
  }
  if (lane < KK) *(ushort*)(TM + lane * PITCH + lane * 2) = 0x3F80;  // M := I

  int eoff[9];  // E-write offsets (step-invariant)
#pragma unroll
  for (int i = 0; i < 9; ++i) {
    int flat = i * 256 + lane * 4;
    int r = flat / 48;
    eoff[i] = r * PITCH + (flat - r * 48) * 2;
  }

  const int t0 = cix << 4;
  const float* tb = scores + ((size_t)b * T_LEN + t0) * (KK * KK);
  const float C1 = 1.4426950408889634f;  // log2(e)
  float4 curv[9], nxtv[9];
  {
    const float4* gp = (const float4*)(tb + (size_t)(steps - 1) * (KK * KK));
#pragma unroll
    for (int i = 0; i < 9; ++i) curv[i] = gp[i * 64 + lane];
  }
  int logE = 0;
  float goldn = 0.0f;

  for (int s = steps - 1; s >= 0; --s) {
    if (s > 0) {  // prefetch next (descending) tile
      const float4* gp = (const float4*)(tb + (size_t)(s - 1) * (KK * KK));
#pragma unroll
      for (int i = 0; i < 9; ++i) nxtv[i] = gp[i * 64 + lane];
    }
    {  // gold: S_t[target] from in-register tile (exact f32)
      int tg = targets[b * T_LEN + t0 + s];
      tg = __builtin_amdgcn_readfirstlane(tg);
      float4 tt;
      switch (tg >> 8) {
        case 0: tt = curv[0]; break; case 1: tt = curv[1]; break;
        case 2: tt = curv[2]; break; case 3: tt = curv[3]; break;
        case 4: tt = curv[4]; break; case 5: tt = curv[5]; break;
        case 6: tt = curv[6]; break; case 7: tt = curv[7]; break;
        default: tt = curv[8]; break;
      }
      int q = tg & 3;
      float cand = (q == 0) ? tt.x : (q == 1) ? tt.y : (q == 2) ? tt.z : tt.w;
      goldn += __shfl(cand, (tg >> 2) & 63);
    }
    // E = exp(S_t), bf16, row-major
#pragma unroll
    for (int i = 0; i < 9; ++i) {
      uint2 pk;
      pk.x = (uint32_t)f2bf(exp2f(curv[i].x * C1)) |
             ((uint32_t)f2bf(exp2f(curv[i].y * C1)) << 16);
      pk.y = (uint32_t)f2bf(exp2f(curv[i].z * C1)) |
             ((uint32_t)f2bf(exp2f(curv[i].w * C1)) << 16);
      *(uint2*)(E + eoff[i]) = pk;
    }
    // A-frags from E (rows), B-frags from TM (cols of M, contiguous) — all b128
    short8 afr[3][2], bfr[2][3];
#pragma unroll
    for (int mi = 0; mi < 3; ++mi)
#pragma unroll
      for (int ki = 0; ki < 2; ++ki)
        afr[mi][ki] = *(const short8*)(E + (mi * 16 + (lane & 15)) * PITCH +
                                       ki * 64 + (lane >> 4) * 16);
#pragma unroll
    for (int ki = 0; ki < 2; ++ki)
#pragma unroll
      for (int ni = 0; ni < 3; ++ni)
        bfr[ki][ni] = *(const short8*)(TM + (ni * 16 + (lane & 15)) * PITCH +
                                       ki * 64 + (lane >> 4) * 16);
    f32x4 acc[3][3];
#pragma unroll
    for (int mi = 0; mi < 3; ++mi)
#pragma unroll
      for (int ni = 0; ni < 3; ++ni) {
        f32x4 d = {0.f, 0.f, 0.f, 0.f};
        d = __builtin_amdgcn_mfma_f32_16x16x32_bf16(afr[mi][0], bfr[0][ni], d, 0, 0, 0);
        d = __builtin_amdgcn_mfma_f32_16x16x32_bf16(afr[mi][1], bfr[1][ni], d, 0, 0, 0);
        acc[mi][ni] = d;
      }
    // periodic exact renorm (exponent strip)
    int it = (steps - 1) - s;
    if (((it & 3) == 3) || s == 0) {
      float mx = 0.0f;
#pragma unroll
      for (int mi = 0; mi < 3; ++mi)
#pragma unroll
        for (int ni = 0; ni < 3; ++ni)
#pragma unroll
          for (int rr = 0; rr < 4; ++rr) mx = fmaxf(mx, acc[mi][ni][rr]);
#pragma unroll
      for (int d = 1; d < 64; d <<= 1) mx = fmaxf(mx, __shfl_xor(mx, d));
      int ex = (int)((__float_as_uint(mx) >> 23) & 255) - 127;
      float sc = __uint_as_float((uint32_t)(127 - ex) << 23);
      logE += ex;
#pragma unroll
      for (int mi = 0; mi < 3; ++mi)
#pragma unroll
        for (int ni = 0; ni < 3; ++ni)
#pragma unroll
          for (int rr = 0; rr < 4; ++rr) acc[mi][ni][rr] *= sc;
    }
    // D -> TM, vectorized 8B stores (col = lane&15, 4 consecutive rows)
#pragma unroll
    for (int ni = 0; ni < 3; ++ni)
#pragma unroll
      for (int mi = 0; mi < 3; ++mi) {
        uint2 pk;
        pk.x = (uint32_t)f2bf(acc[mi][ni][0]) | ((uint32_t)f2bf(acc[mi][ni][1]) << 16);
        pk.y = (uint32_t)f2bf(acc[mi][ni][2]) | ((uint32_t)f2bf(acc[mi][ni][3]) << 16);
        *(uint2*)(TM + (ni * 16 + (lane & 15)) * PITCH + mi * 32 + (lane >> 4) * 8) = pk;
      }
    if (s > 0) {
#pragma unroll
      for (int i = 0; i < 9; ++i) curv[i] = nxtv[i];
    }
  }

  // store transposed chunk matrix densely (48 x 96B)
  unsigned char* gd = wsT + (size_t)g * CHB;
#pragma unroll
  for (int j = 0; j < 9; ++j) {
    int f8 = (j * 64 + lane) * 8;
    int c = f8 / 96;
    *(uint2*)(gd + f8) = *(const uint2*)(TM + c * PITCH + (f8 - c * 96));
  }
  if (lane == 0) {
    wsExpo[g] = logE;
    wsGold[g] = goldn;
  }
}

// ---------------- K3: per-batch combine ----------------
__global__ __launch_bounds__(64) void k3_combine(
    const unsigned char* __restrict__ wsT, const int* __restrict__ wsExpo,
    const float* __restrict__ wsGold, const void* __restrict__ mask,
    float* __restrict__ out) {
  __shared__ float alpha_s[64];
  const int b = blockIdx.x, lane = threadIdx.x & 63;
  const int len = mask_len(mask, b, lane);
  const int nc = (len + 15) >> 4;
  const unsigned char* base = wsT + (size_t)b * 32 * CHB;

  float a = (lane == NSTART) ? 1.0f : 0.0f;
  int expoSum = 0;
  float goldSum = 0.0f;
  uint4 cur[6] = {}, nxt[6] = {};
  if (lane < KK) {
#pragma unroll
    for (int q = 0; q < 6; ++q)
      cur[q] = *(const uint4*)(base + lane * 96 + q * 16);
  }
  for (int c = 0; c < nc; ++c) {
    if (c + 1 < nc && lane < KK) {
#pragma unroll
      for (int q = 0; q < 6; ++q)
        nxt[q] = *(const uint4*)(base + (size_t)(c + 1) * CHB + lane * 96 + q * 16);
    }
    expoSum += wsExpo[b * 32 + c];
    goldSum += wsGold[b * 32 + c];
    alpha_s[lane] = a;
    float s0 = 0.f, s1 = 0.f, s2 = 0.f, s3 = 0.f;
#pragma unroll
    for (int q = 0; q < 6; ++q) {  // lane j: s_j = sum_i alpha_i * TM[j][i]
      uint4 w = cur[q];
      int i0 = q * 8;
      s0 = fmaf(alpha_s[i0 + 0], bf2f(w.x & 0xFFFFu), s0);
      s1 = fmaf(alpha_s[i0 + 1], bf2f(w.x >> 16), s1);
      s2 = fmaf(alpha_s[i0 + 2], bf2f(w.y & 0xFFFFu), s2);
      s3 = fmaf(alpha_s[i0 + 3], bf2f(w.y >> 16), s3);
      s0 = fmaf(alpha_s[i0 + 4], bf2f(w.z & 0xFFFFu), s0);
      s1 = fmaf(alpha_s[i0 + 5], bf2f(w.z >> 16), s1);
      s2 = fmaf(alpha_s[i0 + 6], bf2f(w.w & 0xFFFFu), s2);
      s3 = fmaf(alpha_s[i0 + 7], bf2f(w.w >> 16), s3);
    }
    float s = (s0 + s1) + (s2 + s3);  // lane>=48: cur==0 -> s==0
    float mx = s;
#pragma unroll
    for (int d = 1; d < 64; d <<= 1) mx = fmaxf(mx, __shfl_xor(mx, d));
    int ex = (int)((__float_as_uint(mx) >> 23) & 255) - 127;
    a = s * __uint_as_float((uint32_t)(127 - ex) << 23);
    expoSum += ex;
    if (c + 1 < nc) {
#pragma unroll
      for (int q = 0; q < 6; ++q) cur[q] = nxt[q];
    }
  }
  if (lane == NEND)
    out[b] = 0.69314718055994531f * (log2f(a) + (float)expoSum) - goldSum;
}

extern "C" void kernel_launch(void* const* d_in, const int* in_sizes, int n_in,
                              void* d_out, int out_size, void* d_ws,
                              size_t ws_size, hipStream_t stream) {
  const float* scores = (const float*)d_in[0];
  const int* targets = (const int*)d_in[1];
  const void* mask = (const void*)d_in[2];
  float* out = (float*)d_out;
  const int B = in_sizes[1] / T_LEN;
  const int nch = B * 32;

  unsigned char* wsT = (unsigned char*)d_ws;               // nch * 4608
  int* wsExpo = (int*)(wsT + (size_t)nch * CHB);           // nch ints
  float* wsGold = (float*)(wsExpo + nch);                  // nch floats

  k2_chunks<<<(nch + 3) / 4, 256, 0, stream>>>(scores, targets, mask, wsT,
                                               wsExpo, wsGold, nch);
  k3_combine<<<B, 64, 0, stream>>>(wsT, wsExpo, wsGold, mask, out);
}

// Round 6
// 108.529 us; speedup vs baseline: 1.0085x; 1.0085x over previous
//
#include <hip/hip_runtime.h>
#include <stdint.h>

// CRF forward loss, chunked parallel scan in linear space.
// K2: one wave per 16-step chunk. M <- E_s * M, s descending (=> M = prod
//     ascending). A = E_s rows, B = M via transposed image TM; dense 128B
//     LDS rows with XOR-16B swizzle (phys = logical ^ ((row&7)<<4), full
//     logical offset!) -> all b128 frag reads <=2-way (free).
//     Tile register-prefetched 1 step ahead; targets prefetched per chunk.
//     Balanced mapping b=g%B, cix=g/B evens per-CU work (lengths sorted).
// K3: per-batch serial alpha matvec over <=32 transposed chunk matrices.

#define T_LEN 512
#define KK 48
#define NSTART 46
#define NEND 47
#define RPITCH 128                 // dense row: 64 bf16 (48 real + 16 zero K-pad)
#define REGION (48 * RPITCH)       // 6144 B
#define WAVE_LDS (2 * REGION)      // 12288 B per wave (E + TM)
#define CHB 4608                   // 48x48 bf16 chunk matrix (transposed, pitch 96)

typedef __attribute__((ext_vector_type(8))) short short8;
typedef __attribute__((ext_vector_type(4))) float f32x4;

__device__ __forceinline__ ushort f2bf(float x) {
  uint32_t u = __float_as_uint(x);
  return (ushort)((u + 0x7FFFu + ((u >> 16) & 1u)) >> 16);
}
__device__ __forceinline__ float bf2f(uint32_t h) { return __uint_as_float(h << 16); }

// decode mask encoding (u8 bool / f32 / i32 / i64), popcount row b (prefix mask)
__device__ __forceinline__ int mask_len(const void* mask, int b, int lane) {
  const uint32_t w0 = ((const uint32_t*)mask)[0];
  const uint32_t w1 = ((const uint32_t*)mask)[1];
  int c = 0;
  if (w0 == 0x01010101u) {
    const unsigned long long* m8 =
        (const unsigned long long*)((const unsigned char*)mask + (size_t)b * T_LEN);
    c = (int)__popcll(m8[lane]);
  } else if (w0 == 0x3F800000u) {
    const float* mf = (const float*)mask + (size_t)b * T_LEN;
#pragma unroll
    for (int j = 0; j < 8; ++j) c += (mf[lane + 64 * j] != 0.0f);
  } else if (w1 == 1u) {
    const uint32_t* mi = (const uint32_t*)mask + (size_t)b * T_LEN;
#pragma unroll
    for (int j = 0; j < 8; ++j) c += (mi[lane + 64 * j] != 0u);
  } else {
    const unsigned long long* ml =
        (const unsigned long long*)mask + (size_t)b * T_LEN;
#pragma unroll
    for (int j = 0; j < 8; ++j) c += (ml[lane + 64 * j] != 0ull);
  }
#pragma unroll
  for (int d = 1; d < 64; d <<= 1) c += __shfl_xor(c, d);
  return c > T_LEN ? T_LEN : (c < 0 ? 0 : c);
}

// ---------------- K2: chunk products ----------------
__global__ __launch_bounds__(256, 2) void k2_chunks(
    const float* __restrict__ scores, const int* __restrict__ targets,
    const void* __restrict__ mask, unsigned char* __restrict__ wsT,
    int* __restrict__ wsExpo, float* __restrict__ wsGold, int nch, int B) {
  __shared__ __align__(16) unsigned char smem[4][WAVE_LDS];
  const int wid = threadIdx.x >> 6, lane = threadIdx.x & 63;
  const int g = blockIdx.x * 4 + wid;
  if (g >= nch) return;
  const int cix = g / B;          // balanced: consecutive g -> same cix, diff b
  const int b = g - cix * B;
  const int len = mask_len(mask, b, lane);
  int steps = len - (cix << 4);
  if (steps <= 0) return;  // never consumed by K3
  if (steps > 16) steps = 16;

  unsigned char* E = smem[wid];    // E_s row-major; K-slots 6,7 stay 0 (K-pad)
  unsigned char* TM = E + REGION;  // M transposed; K-pad likewise

  {  // zero both regions: 768 x 16B
    int4* z = (int4*)E;
#pragma unroll
    for (int q = 0; q < 12; ++q) z[q * 64 + lane] = make_int4(0, 0, 0, 0);
  }
  // M := I (swizzled address: full logical offset XOR row-swizzle)
  if (lane < KK)
    *(ushort*)(TM + lane * RPITCH + ((2 * lane) ^ ((lane & 7) << 4))) = 0x3F80;

  const int c15 = lane & 15, h = lane >> 4;
  const int swz = (c15 & 7) << 4;          // row-swizzle for rows ≡ c15 (mod 8)
  const int sl0 = (h * 16) ^ swz;          // K-slot ki=0 read offset
  const int sl1 = (64 + h * 16) ^ swz;     // K-slot ki=1 read offset

  int eoff[9];  // E-write offsets (step-invariant, swizzled)
#pragma unroll
  for (int i = 0; i < 9; ++i) {
    int flat = i * 256 + lane * 4;
    int r = flat / 48;
    eoff[i] = r * RPITCH + ((2 * (flat - r * 48)) ^ ((r & 7) << 4));
  }

  const int t0 = cix << 4;
  const float* tb = scores + ((size_t)b * T_LEN + t0) * (KK * KK);
  int tgt_l = 0;
  if (lane < 16) tgt_l = targets[b * T_LEN + t0 + lane];  // always in-bounds

  const float C1 = 1.4426950408889634f;  // log2(e)
  float4 curv[9], nxtv[9];
  {
    const float4* gp = (const float4*)(tb + (size_t)(steps - 1) * (KK * KK));
#pragma unroll
    for (int i = 0; i < 9; ++i) curv[i] = gp[i * 64 + lane];
  }
  int logE = 0;
  float goldn = 0.0f;

  for (int s = steps - 1; s >= 0; --s) {
    if (s > 0) {  // prefetch next (descending) tile
      const float4* gp = (const float4*)(tb + (size_t)(s - 1) * (KK * KK));
#pragma unroll
      for (int i = 0; i < 9; ++i) nxtv[i] = gp[i * 64 + lane];
    }
    {  // gold += S_s[target] from in-register tile (exact f32)
      int tg = __shfl(tgt_l, s);
      tg = __builtin_amdgcn_readfirstlane(tg);
      float4 tt;
      switch (tg >> 8) {
        case 0: tt = curv[0]; break; case 1: tt = curv[1]; break;
        case 2: tt = curv[2]; break; case 3: tt = curv[3]; break;
        case 4: tt = curv[4]; break; case 5: tt = curv[5]; break;
        case 6: tt = curv[6]; break; case 7: tt = curv[7]; break;
        default: tt = curv[8]; break;
      }
      int q = tg & 3;
      float cand = (q == 0) ? tt.x : (q == 1) ? tt.y : (q == 2) ? tt.z : tt.w;
      goldn += __shfl(cand, (tg >> 2) & 63);
    }
    // E = exp(S_s) bf16, swizzled rows
#pragma unroll
    for (int i = 0; i < 9; ++i) {
      uint2 pk;
      pk.x = (uint32_t)f2bf(exp2f(curv[i].x * C1)) |
             ((uint32_t)f2bf(exp2f(curv[i].y * C1)) << 16);
      pk.y = (uint32_t)f2bf(exp2f(curv[i].z * C1)) |
             ((uint32_t)f2bf(exp2f(curv[i].w * C1)) << 16);
      *(uint2*)(E + eoff[i]) = pk;
    }
    // fragments: all ds_read_b128, <=2-way banked (free)
    short8 afr[3][2], bfr[2][3];
#pragma unroll
    for (int mi = 0; mi < 3; ++mi) {
      afr[mi][0] = *(const short8*)(E + (mi * 16 + c15) * RPITCH + sl0);
      afr[mi][1] = *(const short8*)(E + (mi * 16 + c15) * RPITCH + sl1);
    }
#pragma unroll
    for (int ni = 0; ni < 3; ++ni) {
      bfr[0][ni] = *(const short8*)(TM + (ni * 16 + c15) * RPITCH + sl0);
      bfr[1][ni] = *(const short8*)(TM + (ni * 16 + c15) * RPITCH + sl1);
    }
    f32x4 acc[3][3];
#pragma unroll
    for (int mi = 0; mi < 3; ++mi)
#pragma unroll
      for (int ni = 0; ni < 3; ++ni) {
        f32x4 d = {0.f, 0.f, 0.f, 0.f};
        d = __builtin_amdgcn_mfma_f32_16x16x32_bf16(afr[mi][0], bfr[0][ni], d, 0, 0, 0);
        d = __builtin_amdgcn_mfma_f32_16x16x32_bf16(afr[mi][1], bfr[1][ni], d, 0, 0, 0);
        acc[mi][ni] = d;
      }
    // periodic exact renorm (exponent strip)
    int it = (steps - 1) - s;
    if (((it & 3) == 3) || s == 0) {
      float mx = 0.0f;
#pragma unroll
      for (int mi = 0; mi < 3; ++mi)
#pragma unroll
        for (int ni = 0; ni < 3; ++ni)
#pragma unroll
          for (int rr = 0; rr < 4; ++rr) mx = fmaxf(mx, acc[mi][ni][rr]);
#pragma unroll
      for (int d = 1; d < 64; d <<= 1) mx = fmaxf(mx, __shfl_xor(mx, d));
      int ex = (int)((__float_as_uint(mx) >> 23) & 255) - 127;
      float sc = __uint_as_float((uint32_t)(127 - ex) << 23);
      logE += ex;
#pragma unroll
      for (int mi = 0; mi < 3; ++mi)
#pragma unroll
        for (int ni = 0; ni < 3; ++ni)
#pragma unroll
          for (int rr = 0; rr < 4; ++rr) acc[mi][ni][rr] *= sc;
    }
    // D -> TM, 8B stores. FULL logical offset (mi*32 + h*8) then XOR swizzle —
    // XOR and + don't commute; round-5 bug was mi*32 + (h*8 ^ swz) which can
    // overflow the 128B row into the next TM row.
#pragma unroll
    for (int ni = 0; ni < 3; ++ni)
#pragma unroll
      for (int mi = 0; mi < 3; ++mi) {
        uint2 pk;
        pk.x = (uint32_t)f2bf(acc[mi][ni][0]) | ((uint32_t)f2bf(acc[mi][ni][1]) << 16);
        pk.y = (uint32_t)f2bf(acc[mi][ni][2]) | ((uint32_t)f2bf(acc[mi][ni][3]) << 16);
        *(uint2*)(TM + (ni * 16 + c15) * RPITCH + ((mi * 32 + h * 8) ^ swz)) = pk;
      }
    if (s > 0) {
#pragma unroll
      for (int i = 0; i < 9; ++i) curv[i] = nxtv[i];
    }
  }

  // store transposed chunk matrix densely (48 rows x 96B) at index g = cix*B+b
  unsigned char* gd = wsT + (size_t)g * CHB;
#pragma unroll
  for (int j = 0; j < 9; ++j) {
    int f8 = (j * 64 + lane) * 8;
    int c = f8 / 96;
    int off = f8 - c * 96;
    *(uint2*)(gd + f8) = *(const uint2*)(TM + c * RPITCH + (off ^ ((c & 7) << 4)));
  }
  if (lane == 0) {
    wsExpo[g] = logE;
    wsGold[g] = goldn;
  }
}

// ---------------- K3: per-batch combine ----------------
__global__ __launch_bounds__(64) void k3_combine(
    const unsigned char* __restrict__ wsT, const int* __restrict__ wsExpo,
    const float* __restrict__ wsGold, const void* __restrict__ mask,
    float* __restrict__ out, int B) {
  __shared__ float alpha_s[64];
  const int b = blockIdx.x, lane = threadIdx.x & 63;
  const int len = mask_len(mask, b, lane);
  const int nc = (len + 15) >> 4;

  float a = (lane == NSTART) ? 1.0f : 0.0f;
  int expoSum = 0;
  float goldSum = 0.0f;
  uint4 cur[6] = {}, nxt[6] = {};
  if (lane < KK) {
#pragma unroll
    for (int q = 0; q < 6; ++q)
      cur[q] = *(const uint4*)(wsT + (size_t)b * CHB + lane * 96 + q * 16);
  }
  for (int c = 0; c < nc; ++c) {
    if (c + 1 < nc && lane < KK) {
      const unsigned char* nb = wsT + (size_t)((c + 1) * B + b) * CHB;
#pragma unroll
      for (int q = 0; q < 6; ++q) nxt[q] = *(const uint4*)(nb + lane * 96 + q * 16);
    }
    expoSum += wsExpo[c * B + b];
    goldSum += wsGold[c * B + b];
    alpha_s[lane] = a;
    f32x4 A4[12];
#pragma unroll
    for (int q = 0; q < 12; ++q) A4[q] = *(const f32x4*)&alpha_s[q * 4];
    float s0 = 0.f, s1 = 0.f, s2 = 0.f, s3 = 0.f;
#pragma unroll
    for (int q = 0; q < 6; ++q) {  // lane j: s_j = sum_i alpha_i * TM[j][i]
      uint4 w = cur[q];
      f32x4 a0 = A4[2 * q], a1 = A4[2 * q + 1];
      s0 = fmaf(a0[0], bf2f(w.x & 0xFFFFu), s0);
      s1 = fmaf(a0[1], bf2f(w.x >> 16), s1);
      s2 = fmaf(a0[2], bf2f(w.y & 0xFFFFu), s2);
      s3 = fmaf(a0[3], bf2f(w.y >> 16), s3);
      s0 = fmaf(a1[0], bf2f(w.z & 0xFFFFu), s0);
      s1 = fmaf(a1[1], bf2f(w.z >> 16), s1);
      s2 = fmaf(a1[2], bf2f(w.w & 0xFFFFu), s2);
      s3 = fmaf(a1[3], bf2f(w.w >> 16), s3);
    }
    float s = (s0 + s1) + (s2 + s3);  // lane>=48: cur==0 -> 0
    float mx = s;
#pragma unroll
    for (int d = 1; d < 64; d <<= 1) mx = fmaxf(mx, __shfl_xor(mx, d));
    int ex = (int)((__float_as_uint(mx) >> 23) & 255) - 127;
    a = s * __uint_as_float((uint32_t)(127 - ex) << 23);
    expoSum += ex;
    if (c + 1 < nc) {
#pragma unroll
      for (int q = 0; q < 6; ++q) cur[q] = nxt[q];
    }
  }
  if (lane == NEND)
    out[b] = 0.69314718055994531f * (log2f(a) + (float)expoSum) - goldSum;
}

extern "C" void kernel_launch(void* const* d_in, const int* in_sizes, int n_in,
                              void* d_out, int out_size, void* d_ws,
                              size_t ws_size, hipStream_t stream) {
  const float* scores = (const float*)d_in[0];
  const int* targets = (const int*)d_in[1];
  const void* mask = (const void*)d_in[2];
  float* out = (float*)d_out;
  const int B = in_sizes[1] / T_LEN;
  const int nch = B * 32;

  unsigned char* wsT = (unsigned char*)d_ws;      // nch * 4608
  int* wsExpo = (int*)(wsT + (size_t)nch * CHB);  // nch ints
  float* wsGold = (float*)(wsExpo + nch);         // nch floats

  k2_chunks<<<(nch + 3) / 4, 256, 0, stream>>>(scores, targets, mask, wsT,
                                               wsExpo, wsGold, nch, B);
  k3_combine<<<B, 64, 0, stream>>>(wsT, wsExpo, wsGold, mask, out, B);
}